// Round 26
// baseline (626.695 us; speedup 1.0000x reference)
//
#include <hip/hip_runtime.h>
#include <math.h>

#define HH 64
#define WW 96
#define NPX (HH*WW)        // 6144
#define CIN 1024
#define CMID 512
#define NA 9
#define NANCH (NPX*NA)     // 55296
#define PRE_NMS 6000
#define POST_NMS 300
#define NEGV -1e9f
#define NBINS 16384
#define BUFCAP 8192
#define MASKW 94           // ceil(6000/64)

#define PYS 66             // padded rows
#define PXS 98             // padded cols
#define NCB 32             // channel blocks of 32
#define SCL 2048.0f
#define INV_SCL (1.0f/2048.0f)

// conv1x1 tiling
#define K2_CS 16
#define K2_CC (CMID/K2_CS) // 32

typedef _Float16 f16x8 __attribute__((ext_vector_type(8)));
typedef float f32x4 __attribute__((ext_vector_type(4)));

__constant__ float c_anch[9][4] = {
    {-84.f, -40.f,  99.f,  55.f},
    {-176.f,-88.f, 191.f, 103.f},
    {-360.f,-184.f,375.f, 199.f},
    {-56.f, -56.f,  71.f,  71.f},
    {-120.f,-120.f,135.f, 135.f},
    {-248.f,-248.f,263.f, 263.f},
    {-36.f, -80.f,  51.f,  95.f},
    {-80.f,-168.f,  95.f, 183.f},
    {-168.f,-344.f,183.f, 359.f}
};

__device__ __forceinline__ unsigned int fkey(float f) {
    unsigned int b = __float_as_uint(f);
    return (b & 0x80000000u) ? ~b : (b | 0x80000000u);
}
__device__ __forceinline__ float fkey_inv(unsigned int k) {
    unsigned int b = (k & 0x80000000u) ? (k & 0x7fffffffu) : ~k;
    return __uint_as_float(b);
}
__device__ __forceinline__ int score_bin(float s) {
    if (!(s > 0.f)) return 0;
    int b = (int)(s * (float)NBINS);
    return b > NBINS - 1 ? NBINS - 1 : b;
}

// ---------------- P1: x[c][p] -> blocked [cb][py][px][c32] f16 hi/lo ----------------
__global__ __launch_bounds__(256) void prep_x(const float* __restrict__ x,
                                              _Float16* __restrict__ xh,
                                              _Float16* __restrict__ xl) {
    __shared__ float t[64][65];
    int tid = threadIdx.x;
    int c0 = blockIdx.x * 64;
    int p0 = blockIdx.y * 64;
    int g = tid >> 6, l = tid & 63;
#pragma unroll
    for (int k = 0; k < 16; k++) {
        int cl = g * 16 + k;
        t[cl][l] = x[(size_t)(c0 + cl) * NPX + p0 + l];
    }
    __syncthreads();
#pragma unroll
    for (int k = 0; k < 16; k++) {
        int pl = g * 16 + k;
        int p = p0 + pl;
        int y = p / WW, xc = p - y * WW;
        int c = c0 + l;
        float v = t[l][pl];
        _Float16 hv = (_Float16)v;
        _Float16 lv = (_Float16)((v - (float)hv) * SCL);
        size_t o = (((size_t)(c >> 5) * PYS + (y + 1)) * PXS + (xc + 1)) * 32 + (c & 31);
        xh[o] = hv;
        xl[o] = lv;
    }
}

// ---------------- P2: w[oc][c][tap] -> blocked [tap][cb][oc][c32] f16 hi/lo ----------------
__global__ __launch_bounds__(256) void prep_w(const float* __restrict__ w,
                                              _Float16* __restrict__ wh,
                                              _Float16* __restrict__ wl) {
    __shared__ _Float16 sh[CIN * 9];
    __shared__ _Float16 sl[CIN * 9];
    int tid = threadIdx.x;
    int oc = blockIdx.x;
    for (int i = tid; i < CIN * 9; i += 256) {
        float v = w[(size_t)oc * CIN * 9 + i];     // i = c*9 + tap
        _Float16 hv = (_Float16)v;
        sh[i] = hv;
        sl[i] = (_Float16)((v - (float)hv) * SCL);
    }
    __syncthreads();
    for (int i = tid; i < CIN * 9; i += 256) {     // i = tap*1024 + c
        int tap = i >> 10;
        int c = i & 1023;
        size_t o = (((size_t)tap * NCB + (c >> 5)) * CMID + oc) * 32 + (c & 31);
        wh[o] = sh[c * 9 + tap];
        wl[o] = sl[c * 9 + tap];
    }
}

// ---------------- K1: 3x3 conv via MFMA f16x3, K-split-by-wave, A-row reuse ----------------
// Proven 242-us dataflow (rounds 19/20/22/23/25) + LOCALITY SWIZZLE:
// decompose bid so oc-group varies FASTEST and each XCD owns a contiguous
// 12-tile spatial slab. The 16 blocks sharing an A tile become temporally
// adjacent on one XCD; with blocks phase-locked in cb, the instantaneous
// footprint is ~6 tiles x 73KB (A) + 1.2MB (B phase slice) ~ 1.6MB < 4MB L2
// -> A loads become L2 hits instead of L3 (~600cy) misses.
// (Round-15's failed swizzle was the OPPOSITE grouping: all 96 spatial
// tiles per XCD -> thrash. Old mapping spread A-sharers 96 bids apart.)
__global__ __launch_bounds__(256, 3) void conv3_mfma(const _Float16* __restrict__ xh,
                                                     const _Float16* __restrict__ xl,
                                                     const _Float16* __restrict__ wh,
                                                     const _Float16* __restrict__ wl,
                                                     const float* __restrict__ b1,
                                                     float* __restrict__ h) {
    __shared__ float4 red[4][2][64];    // 8 KB
    int tid = threadIdx.x;
    int lane = tid & 63;
    int wv = tid >> 6;
    int bid = blockIdx.x + 96 * blockIdx.y;   // dispatch order, x fastest
    int xcd = bid & 7;
    int idx = bid >> 3;                 // temporal order within XCD (assumed RR)
    int ocg = idx & 15;                 // oc-group varies fastest
    int spl = idx >> 4;                 // 0..11
    int sp  = xcd * 12 + spl;           // each XCD owns 12 spatial tiles
    int ty0 = (sp / 6) * 4;
    int tx0 = (sp % 6) * 16;
    int oc0 = ocg * 32;

    int la = lane & 15;
    int kg = lane >> 4;

    f32x4 acch[4][2], accc[4][2];
#pragma unroll
    for (int m = 0; m < 4; m++)
#pragma unroll
        for (int n = 0; n < 2; n++) {
            acch[m][n] = (f32x4){0.f, 0.f, 0.f, 0.f};
            accc[m][n] = (f32x4){0.f, 0.f, 0.f, 0.f};
        }

    int cb0 = wv * (NCB / 4);
    for (int cbi = 0; cbi < NCB / 4; cbi++) {
        int cb = cb0 + cbi;
#pragma unroll
        for (int kx = 0; kx < 3; kx++) {
            f16x8 a6h[6], a6l[6];
#pragma unroll
            for (int r = 0; r < 6; r++) {
                int aoff = ((cb * PYS + (ty0 + r)) * PXS + (tx0 + kx + la)) * 32 + kg * 8;
                a6h[r] = *(const f16x8*)(xh + aoff);
                a6l[r] = *(const f16x8*)(xl + aoff);
            }
#pragma unroll
            for (int ky = 0; ky < 3; ky++) {
                const int tap = ky * 3 + kx;
#pragma unroll
                for (int n = 0; n < 2; n++) {
                    int boff = ((tap * NCB + cb) * CMID + oc0 + n * 16 + la) * 32 + kg * 8;
                    f16x8 bh = *(const f16x8*)(wh + boff);
                    f16x8 bl = *(const f16x8*)(wl + boff);
#pragma unroll
                    for (int m = 0; m < 4; m++) {
                        acch[m][n] = __builtin_amdgcn_mfma_f32_16x16x32_f16(a6h[m + ky], bh, acch[m][n], 0, 0, 0);
                        accc[m][n] = __builtin_amdgcn_mfma_f32_16x16x32_f16(a6l[m + ky], bh, accc[m][n], 0, 0, 0);
                        accc[m][n] = __builtin_amdgcn_mfma_f32_16x16x32_f16(a6h[m + ky], bl, accc[m][n], 0, 0, 0);
                    }
                }
            }
        }
    }

#pragma unroll
    for (int m = 0; m < 4; m++) {
        __syncthreads();
#pragma unroll
        for (int n = 0; n < 2; n++) {
            f32x4 t = acch[m][n];
            f32x4 c = accc[m][n];
            float4 w4;
            w4.x = t[0] + c[0] * INV_SCL;
            w4.y = t[1] + c[1] * INV_SCL;
            w4.z = t[2] + c[2] * INV_SCL;
            w4.w = t[3] + c[3] * INV_SCL;
            red[wv][n][lane] = w4;
        }
        __syncthreads();
        if (tid < 128) {
            int n = tid >> 6, l = tid & 63;
            float4 s0 = red[0][n][l], s1 = red[1][n][l];
            float4 s2 = red[2][n][l], s3 = red[3][n][l];
            int oc = oc0 + n * 16 + (l & 15);
            float bs = b1[oc];
            float4 s;
            s.x = fmaxf(s0.x + s1.x + s2.x + s3.x + bs, 0.f);
            s.y = fmaxf(s0.y + s1.y + s2.y + s3.y + bs, 0.f);
            s.z = fmaxf(s0.z + s1.z + s2.z + s3.z + bs, 0.f);
            s.w = fmaxf(s0.w + s1.w + s2.w + s3.w + bs, 0.f);
            int y = ty0 + m;
            int px0 = tx0 + (l >> 4) * 4;
            *(float4*)&h[(size_t)oc * NPX + y * WW + px0] = s;
        }
    }
}

// ---------------- K2: 1x1 convs (c-split partials) ----------------
__global__ __launch_bounds__(256) void conv1x1_part(const float* __restrict__ h,
                                                    const float* __restrict__ wc,
                                                    const float* __restrict__ wb,
                                                    float* __restrict__ psum) {
    __shared__ float wT[K2_CC][56];
    int tid = threadIdx.x;
    int px = blockIdx.x * 256 + tid;
    int g = blockIdx.y;
    int cb = g * K2_CC;
    for (int i = tid; i < K2_CC * 54; i += 256) {
        int c = i / 54, o = i - c * 54;
        float wv = (o < 18) ? wc[o * CMID + cb + c] : wb[(o - 18) * CMID + cb + c];
        wT[c][o] = wv;
    }
    __syncthreads();
    float acc[54];
#pragma unroll
    for (int o = 0; o < 54; o++) acc[o] = 0.f;
    for (int c = 0; c < K2_CC; c++) {
        float hv = h[(size_t)(cb + c) * NPX + px];
#pragma unroll
        for (int o = 0; o < 54; o++) acc[o] += wT[c][o] * hv;
    }
    for (int o = 0; o < 54; o++)
        psum[((size_t)g * 54 + o) * NPX + px] = acc[o];
}

// ---------------- K2b+K3 fused: reduce psum + proposals + histogram ----------------
__global__ __launch_bounds__(256) void fused_props(const float* __restrict__ psum,
                                                   const float* __restrict__ bc,
                                                   const float* __restrict__ bb,
                                                   const float* __restrict__ info,
                                                   float* __restrict__ props,
                                                   float* __restrict__ scv,
                                                   unsigned int* __restrict__ hist) {
    int i = blockIdx.x * 256 + threadIdx.x;
    if (i >= NANCH) return;
    int a = i / NPX;          // 0..8 (block-uniform: NPX % 256 == 0)
    int p = i - a * NPX;
    int hy = p / WW, wx = p - hy * WW;

    float v0 = bc[a];
    float v1 = bc[a + 9];
    float v2 = bb[4 * a + 0];
    float v3 = bb[4 * a + 1];
    float v4 = bb[4 * a + 2];
    float v5 = bb[4 * a + 3];
    for (int g = 0; g < K2_CS; g++) {
        const float* pg = psum + ((size_t)g * 54) * NPX + p;
        v0 += pg[(size_t)a * NPX];
        v1 += pg[(size_t)(a + 9) * NPX];
        v2 += pg[(size_t)(18 + 4 * a + 0) * NPX];
        v3 += pg[(size_t)(18 + 4 * a + 1) * NPX];
        v4 += pg[(size_t)(18 + 4 * a + 2) * NPX];
        v5 += pg[(size_t)(18 + 4 * a + 3) * NPX];
    }

    float m = fmaxf(v0, v1);
    float e0 = expf(v0 - m), e1 = expf(v1 - m);
    float fg = e1 / (e0 + e1);

    float sx = wx * 16.f, sy = hy * 16.f;
    float ax1 = c_anch[a][0] + sx, ay1 = c_anch[a][1] + sy;
    float ax2 = c_anch[a][2] + sx, ay2 = c_anch[a][3] + sy;
    float wdt = ax2 - ax1 + 1.f;
    float hgt = ay2 - ay1 + 1.f;
    float cx = ax1 + 0.5f * wdt;
    float cy = ay1 + 0.5f * hgt;
    float pcx = v2 * wdt + cx;
    float pcy = v3 * hgt + cy;
    float pw = expf(v4) * wdt;
    float ph = expf(v5) * hgt;

    float imh = info[0], imw = info[1], iscale = info[2];
    float x1 = fminf(fmaxf(pcx - 0.5f * pw, 0.f), imw - 1.f);
    float y1 = fminf(fmaxf(pcy - 0.5f * ph, 0.f), imh - 1.f);
    float x2 = fminf(fmaxf(pcx + 0.5f * pw, 0.f), imw - 1.f);
    float y2 = fminf(fmaxf(pcy + 0.5f * ph, 0.f), imh - 1.f);

    float ms = 16.f * iscale;
    bool valid = ((x2 - x1 + 1.f) >= ms) && ((y2 - y1 + 1.f) >= ms);
    float s = valid ? fg : NEGV;

    int id = p * NA + a;                 // anchor index in reference (h,w,a) order
    props[(size_t)id * 4 + 0] = x1;
    props[(size_t)id * 4 + 1] = y1;
    props[(size_t)id * 4 + 2] = x2;
    props[(size_t)id * 4 + 3] = y2;
    scv[id] = s;
    atomicAdd(&hist[score_bin(s)], 1u);
}

// ---------------- K4: find threshold bin ----------------
__global__ __launch_bounds__(1024) void scan_hist(const unsigned int* __restrict__ hist,
                                                  unsigned int* __restrict__ params) {
    __shared__ unsigned int psum[1024];
    int tid = threadIdx.x;
    unsigned int s = 0;
    for (int k = 0; k < 16; k++) s += hist[tid * 16 + k];
    psum[tid] = s;
    __syncthreads();
    if (tid == 0) {
        unsigned int run = 0;
        int B = 0;
        int t;
        for (t = 1023; t >= 0; t--) {
            if (run + psum[t] >= PRE_NMS) break;
            run += psum[t];
        }
        if (t >= 0) {
            unsigned int r2 = run;
            B = t * 16;
            for (int b = t * 16 + 15; b >= t * 16; b--) {
                r2 += hist[b];
                if (r2 >= PRE_NMS) { B = b; break; }
            }
        }
        params[0] = (unsigned int)B;
    }
}

// ---------------- K5: gather candidates ----------------
__global__ __launch_bounds__(256) void gather_top(const float* __restrict__ scv,
                                                  const unsigned int* __restrict__ params,
                                                  unsigned long long* __restrict__ buf,
                                                  unsigned int* __restrict__ counter) {
    int i = blockIdx.x * 256 + threadIdx.x;
    if (i >= NANCH) return;
    float s = scv[i];
    if (score_bin(s) >= (int)params[0]) {
        unsigned int pos = atomicAdd(counter, 1u);
        if (pos < BUFCAP) {
            unsigned long long key = ((unsigned long long)fkey(s) << 32) |
                                     (unsigned int)(~(unsigned int)i);
            buf[pos] = key;
        }
    }
}

// ---------------- K6: bitonic sort (shfl-accelerated), emit top-6000 ----------------
__global__ __launch_bounds__(1024) void sort_top(unsigned long long* __restrict__ buf,
                                                 const unsigned int* __restrict__ counter,
                                                 const float* __restrict__ props,
                                                 float* __restrict__ top_boxes,
                                                 float* __restrict__ top_sc) {
    __shared__ unsigned long long arr[BUFCAP];   // 64 KiB
    int tid = threadIdx.x;
    int lane = tid & 63;
    int wvid = tid >> 6;
    unsigned int m = counter[0];
    if (m > BUFCAP) m = BUFCAP;
    for (int i = tid; i < BUFCAP; i += 1024) arr[i] = (i < (int)m) ? buf[i] : 0ULL;
    __syncthreads();
    for (int k = 2; k <= BUFCAP; k <<= 1) {
        for (int j = k >> 1; j >= 64; j >>= 1) {
            for (int i = tid; i < BUFCAP; i += 1024) {
                int l = i ^ j;
                if (l > i) {
                    unsigned long long a = arr[i], b = arr[l];
                    bool dir = ((i & k) == 0);   // descending overall
                    if (dir ? (a < b) : (a > b)) { arr[i] = b; arr[l] = a; }
                }
            }
            __syncthreads();
        }
        int jstart = (k >> 1) < 32 ? (k >> 1) : 32;
        for (int seg = wvid; seg < BUFCAP / 64; seg += 16) {
            int i = seg * 64 + lane;
            unsigned long long v = arr[i];
            bool dir = ((i & k) == 0);
            for (int j = jstart; j >= 1; j >>= 1) {
                unsigned long long v2 = __shfl_xor(v, j);
                bool islo = ((lane & j) == 0);
                unsigned long long vmin = v < v2 ? v : v2;
                unsigned long long vmax = v < v2 ? v2 : v;
                v = (dir == islo) ? vmax : vmin;
            }
            arr[i] = v;
        }
        __syncthreads();
    }
    for (int t = tid; t < PRE_NMS; t += 1024) {
        unsigned long long v = arr[t];
        unsigned int key = (unsigned int)(v >> 32);
        unsigned int idx = ~((unsigned int)v);
        top_sc[t] = fkey_inv(key);
        float4 bx = *(const float4*)&props[(size_t)idx * 4];
        *(float4*)&top_boxes[(size_t)t * 4] = bx;
    }
}

// ---------------- K7a: all-pairs IoU bitmask (upper triangle) ----------------
__global__ __launch_bounds__(256) void iou_mask(const float* __restrict__ top_boxes,
                                                unsigned long long* __restrict__ mask) {
    int wid = (blockIdx.x * 256 + threadIdx.x) >> 6;
    int lane = threadIdx.x & 63;
    if (wid >= PRE_NMS) return;
    float4 b = *(const float4*)&top_boxes[(size_t)wid * 4];
    float ab = (b.z - b.x + 1.f) * (b.w - b.y + 1.f);
    for (int cj = 0; cj < MASKW; cj++) {
        unsigned long long m = 0ULL;
        if ((cj + 1) * 64 > wid) {
            int j = cj * 64 + lane;
            bool sup = false;
            if (j < PRE_NMS && j >= wid) {
                float4 c = *(const float4*)&top_boxes[(size_t)j * 4];
                float ac = (c.z - c.x + 1.f) * (c.w - c.y + 1.f);
                float ix1 = fmaxf(b.x, c.x), iy1 = fmaxf(b.y, c.y);
                float ix2 = fminf(b.z, c.z), iy2 = fminf(b.w, c.w);
                float inter = fmaxf(ix2 - ix1 + 1.f, 0.f) * fmaxf(iy2 - iy1 + 1.f, 0.f);
                float iou = inter / (ab + ac - inter);
                sup = iou > 0.7f;
            }
            m = __ballot(sup);
        }
        if (lane == 0) mask[(size_t)wid * MASKW + cj] = m;
    }
}

// ---------------- K7b: greedy walk over sorted list ----------------
__global__ __launch_bounds__(64) void nms_greedy(const float* __restrict__ top_boxes,
                                                 const unsigned long long* __restrict__ mask,
                                                 float* __restrict__ out) {
    int lane = threadIdx.x;
    unsigned long long r0 = 0ULL;
    unsigned long long r1;
    if (lane < 29)      r1 = 0ULL;
    else if (lane == 29) r1 = ~((1ULL << 48) - 1);
    else                r1 = ~0ULL;
    for (int t = 0; t < POST_NMS; t++) {
        unsigned long long w0 = ~r0;
        unsigned long long w1 = ~r1;
        unsigned long long B0 = __ballot(w0 != 0ULL);
        unsigned long long B1 = __ballot(w1 != 0ULL);
        int pos = 0;
        if (B0) {
            int wl = __builtin_ctzll(B0);
            unsigned long long bits = __shfl(w0, wl);
            pos = wl * 64 + __builtin_ctzll(bits);
        } else if (B1) {
            int wl = __builtin_ctzll(B1);
            unsigned long long bits = __shfl(w1, wl);
            pos = (64 + wl) * 64 + __builtin_ctzll(bits);
        }
        if (lane == 0) {
            float4 bb = *(const float4*)&top_boxes[(size_t)pos * 4];
            out[t * 5 + 0] = 0.f;
            out[t * 5 + 1] = bb.x;
            out[t * 5 + 2] = bb.y;
            out[t * 5 + 3] = bb.z;
            out[t * 5 + 4] = bb.w;
        }
        r0 |= mask[(size_t)pos * MASKW + lane];
        if (lane < 30) r1 |= mask[(size_t)pos * MASKW + 64 + lane];
    }
}

// ---------------- launch ----------------
extern "C" void kernel_launch(void* const* d_in, const int* in_sizes, int n_in,
                              void* d_out, int out_size, void* d_ws, size_t ws_size,
                              hipStream_t stream) {
    const float* base = (const float*)d_in[0];
    const float* info = (const float*)d_in[1];
    const float* W1 = (const float*)d_in[3];
    const float* b1 = (const float*)d_in[4];
    const float* Wc = (const float*)d_in[5];
    const float* bc = (const float*)d_in[6];
    const float* Wb = (const float*)d_in[7];
    const float* Bb = (const float*)d_in[8];
    float* out = (float*)d_out;
    char* ws = (char*)d_ws;

    // Proven round-14 layout (60.6 MB extent). Only psum and mask alias
    // (xh region, dead after conv3_mfma / fused_props respectively).
    const size_t SZ_XT = (size_t)PYS * PXS * CIN * 2;        // 13,246,464
    const size_t SZ_WT = (size_t)9 * CMID * CIN * 2;         // 9,437,184
    const size_t OFF_XH = 0;
    const size_t OFF_XL = OFF_XH + SZ_XT;
    const size_t OFF_WH = OFF_XL + SZ_XT;
    const size_t OFF_WL = OFF_WH + SZ_WT;
    const size_t OFF_H  = OFF_WL + SZ_WT;                    // 45.4 MB
    const size_t OFF_SD   = OFF_H + (size_t)CMID * NPX * 4;  // 58.0 MB (spacer)
    const size_t OFF_PROPS= OFF_SD + (size_t)54 * NPX * 4;
    const size_t OFF_SCV  = OFF_PROPS + (size_t)NANCH * 16;
    const size_t OFF_HIST = OFF_SCV + (size_t)NANCH * 4;
    const size_t OFF_PAR  = OFF_HIST + (size_t)NBINS * 4;
    const size_t OFF_BUF  = OFF_PAR + 256;
    const size_t OFF_TB   = OFF_BUF + (size_t)BUFCAP * 8;
    const size_t OFF_TS   = OFF_TB + (size_t)PRE_NMS * 16;   // ends 60.6 MB
    const size_t OFF_PSUM = OFF_XH;                          // 21.2MB <- xh/xl dead
    const size_t OFF_MASK = OFF_XH;                          // 4.5MB <- psum dead

    _Float16* xh = (_Float16*)(ws + OFF_XH);
    _Float16* xl = (_Float16*)(ws + OFF_XL);
    _Float16* wh = (_Float16*)(ws + OFF_WH);
    _Float16* wl = (_Float16*)(ws + OFF_WL);
    float* h  = (float*)(ws + OFF_H);
    float* psum = (float*)(ws + OFF_PSUM);
    unsigned long long* mask = (unsigned long long*)(ws + OFF_MASK);
    float* props = (float*)(ws + OFF_PROPS);
    float* scv = (float*)(ws + OFF_SCV);
    unsigned int* hist = (unsigned int*)(ws + OFF_HIST);
    unsigned int* params = (unsigned int*)(ws + OFF_PAR);
    unsigned int* counter = params + 1;
    unsigned long long* buf = (unsigned long long*)(ws + OFF_BUF);
    float* top_boxes = (float*)(ws + OFF_TB);
    float* top_sc = (float*)(ws + OFF_TS);

    hipMemsetAsync(xh, 0, SZ_XT * 2, stream);    // zero xh+xl (contiguous) for halo
    hipMemsetAsync(hist, 0, (size_t)NBINS * 4 + 256, stream);

    prep_x<<<dim3(CIN / 64, NPX / 64), 256, 0, stream>>>(base, xh, xl);
    prep_w<<<CMID, 256, 0, stream>>>(W1, wh, wl);
    conv3_mfma<<<dim3(96, 16), 256, 0, stream>>>(xh, xl, wh, wl, b1, h);
    conv1x1_part<<<dim3(NPX / 256, K2_CS), 256, 0, stream>>>(h, Wc, Wb, psum);
    fused_props<<<NANCH / 256, 256, 0, stream>>>(psum, bc, Bb, info, props, scv, hist);
    scan_hist<<<1, 1024, 0, stream>>>(hist, params);
    gather_top<<<NANCH / 256, 256, 0, stream>>>(scv, params, buf, counter);
    sort_top<<<1, 1024, 0, stream>>>(buf, counter, props, top_boxes, top_sc);
    iou_mask<<<(PRE_NMS * 64 + 255) / 256, 256, 0, stream>>>(top_boxes, mask);
    nms_greedy<<<1, 64, 0, stream>>>(top_boxes, mask, out);
}

// Round 27
// 598.446 us; speedup vs baseline: 1.0472x; 1.0472x over previous
//
#include <hip/hip_runtime.h>
#include <math.h>

#define HH 64
#define WW 96
#define NPX (HH*WW)        // 6144
#define CIN 1024
#define CMID 512
#define NA 9
#define NANCH (NPX*NA)     // 55296
#define PRE_NMS 6000
#define POST_NMS 300
#define NEGV -1e9f
#define NBINS 16384
#define BUFCAP 8192
#define MASKW 94           // ceil(6000/64)

#define PYS 66             // padded rows
#define PXS 98             // padded cols
#define NCB 32             // channel blocks of 32
#define SCL 2048.0f
#define INV_SCL (1.0f/2048.0f)

// conv1x1 tiling
#define K2_CS 16
#define K2_CC (CMID/K2_CS) // 32

typedef _Float16 f16x8 __attribute__((ext_vector_type(8)));
typedef float f32x4 __attribute__((ext_vector_type(4)));

__constant__ float c_anch[9][4] = {
    {-84.f, -40.f,  99.f,  55.f},
    {-176.f,-88.f, 191.f, 103.f},
    {-360.f,-184.f,375.f, 199.f},
    {-56.f, -56.f,  71.f,  71.f},
    {-120.f,-120.f,135.f, 135.f},
    {-248.f,-248.f,263.f, 263.f},
    {-36.f, -80.f,  51.f,  95.f},
    {-80.f,-168.f,  95.f, 183.f},
    {-168.f,-344.f,183.f, 359.f}
};

__device__ __forceinline__ unsigned int fkey(float f) {
    unsigned int b = __float_as_uint(f);
    return (b & 0x80000000u) ? ~b : (b | 0x80000000u);
}
__device__ __forceinline__ float fkey_inv(unsigned int k) {
    unsigned int b = (k & 0x80000000u) ? (k & 0x7fffffffu) : ~k;
    return __uint_as_float(b);
}
__device__ __forceinline__ int score_bin(float s) {
    if (!(s > 0.f)) return 0;
    int b = (int)(s * (float)NBINS);
    return b > NBINS - 1 ? NBINS - 1 : b;
}

// ---------------- P1: x[c][p] -> blocked [cb][py][px][c32] f16 hi/lo ----------------
__global__ __launch_bounds__(256) void prep_x(const float* __restrict__ x,
                                              _Float16* __restrict__ xh,
                                              _Float16* __restrict__ xl) {
    __shared__ float t[64][65];
    int tid = threadIdx.x;
    int c0 = blockIdx.x * 64;
    int p0 = blockIdx.y * 64;
    int g = tid >> 6, l = tid & 63;
#pragma unroll
    for (int k = 0; k < 16; k++) {
        int cl = g * 16 + k;
        t[cl][l] = x[(size_t)(c0 + cl) * NPX + p0 + l];
    }
    __syncthreads();
#pragma unroll
    for (int k = 0; k < 16; k++) {
        int pl = g * 16 + k;
        int p = p0 + pl;
        int y = p / WW, xc = p - y * WW;
        int c = c0 + l;
        float v = t[l][pl];
        _Float16 hv = (_Float16)v;
        _Float16 lv = (_Float16)((v - (float)hv) * SCL);
        size_t o = (((size_t)(c >> 5) * PYS + (y + 1)) * PXS + (xc + 1)) * 32 + (c & 31);
        xh[o] = hv;
        xl[o] = lv;
    }
}

// ---------------- P2: w[oc][c][tap] -> blocked [tap][cb][oc][c32] f16 hi/lo ----------------
__global__ __launch_bounds__(256) void prep_w(const float* __restrict__ w,
                                              _Float16* __restrict__ wh,
                                              _Float16* __restrict__ wl) {
    __shared__ _Float16 sh[CIN * 9];
    __shared__ _Float16 sl[CIN * 9];
    int tid = threadIdx.x;
    int oc = blockIdx.x;
    for (int i = tid; i < CIN * 9; i += 256) {
        float v = w[(size_t)oc * CIN * 9 + i];     // i = c*9 + tap
        _Float16 hv = (_Float16)v;
        sh[i] = hv;
        sl[i] = (_Float16)((v - (float)hv) * SCL);
    }
    __syncthreads();
    for (int i = tid; i < CIN * 9; i += 256) {     // i = tap*1024 + c
        int tap = i >> 10;
        int c = i & 1023;
        size_t o = (((size_t)tap * NCB + (c >> 5)) * CMID + oc) * 32 + (c & 31);
        wh[o] = sh[c * 9 + tap];
        wl[o] = sl[c * 9 + tap];
    }
}

// ---------------- K1: 3x3 conv via MFMA f16x3, K-split-by-wave, A-row reuse ----------------
// Proven 242-us version (rounds 19/20/22/23/25). Scheduling interventions
// (r15/r21/r24) and locality swizzles in BOTH directions (r15, r26) all
// regressed; the natural dispatch order (sp fastest -> consecutive blocks
// share the B stream) is the best measured configuration.
__global__ __launch_bounds__(256, 3) void conv3_mfma(const _Float16* __restrict__ xh,
                                                     const _Float16* __restrict__ xl,
                                                     const _Float16* __restrict__ wh,
                                                     const _Float16* __restrict__ wl,
                                                     const float* __restrict__ b1,
                                                     float* __restrict__ h) {
    __shared__ float4 red[4][2][64];    // 8 KB
    int tid = threadIdx.x;
    int lane = tid & 63;
    int wv = tid >> 6;
    int sp = blockIdx.x;
    int ty0 = (sp / 6) * 4;
    int tx0 = (sp % 6) * 16;
    int oc0 = blockIdx.y * 32;

    int la = lane & 15;
    int kg = lane >> 4;

    f32x4 acch[4][2], accc[4][2];
#pragma unroll
    for (int m = 0; m < 4; m++)
#pragma unroll
        for (int n = 0; n < 2; n++) {
            acch[m][n] = (f32x4){0.f, 0.f, 0.f, 0.f};
            accc[m][n] = (f32x4){0.f, 0.f, 0.f, 0.f};
        }

    int cb0 = wv * (NCB / 4);
    for (int cbi = 0; cbi < NCB / 4; cbi++) {
        int cb = cb0 + cbi;
#pragma unroll
        for (int kx = 0; kx < 3; kx++) {
            f16x8 a6h[6], a6l[6];
#pragma unroll
            for (int r = 0; r < 6; r++) {
                int aoff = ((cb * PYS + (ty0 + r)) * PXS + (tx0 + kx + la)) * 32 + kg * 8;
                a6h[r] = *(const f16x8*)(xh + aoff);
                a6l[r] = *(const f16x8*)(xl + aoff);
            }
#pragma unroll
            for (int ky = 0; ky < 3; ky++) {
                const int tap = ky * 3 + kx;
#pragma unroll
                for (int n = 0; n < 2; n++) {
                    int boff = ((tap * NCB + cb) * CMID + oc0 + n * 16 + la) * 32 + kg * 8;
                    f16x8 bh = *(const f16x8*)(wh + boff);
                    f16x8 bl = *(const f16x8*)(wl + boff);
#pragma unroll
                    for (int m = 0; m < 4; m++) {
                        acch[m][n] = __builtin_amdgcn_mfma_f32_16x16x32_f16(a6h[m + ky], bh, acch[m][n], 0, 0, 0);
                        accc[m][n] = __builtin_amdgcn_mfma_f32_16x16x32_f16(a6l[m + ky], bh, accc[m][n], 0, 0, 0);
                        accc[m][n] = __builtin_amdgcn_mfma_f32_16x16x32_f16(a6h[m + ky], bl, accc[m][n], 0, 0, 0);
                    }
                }
            }
        }
    }

#pragma unroll
    for (int m = 0; m < 4; m++) {
        __syncthreads();
#pragma unroll
        for (int n = 0; n < 2; n++) {
            f32x4 t = acch[m][n];
            f32x4 c = accc[m][n];
            float4 w4;
            w4.x = t[0] + c[0] * INV_SCL;
            w4.y = t[1] + c[1] * INV_SCL;
            w4.z = t[2] + c[2] * INV_SCL;
            w4.w = t[3] + c[3] * INV_SCL;
            red[wv][n][lane] = w4;
        }
        __syncthreads();
        if (tid < 128) {
            int n = tid >> 6, l = tid & 63;
            float4 s0 = red[0][n][l], s1 = red[1][n][l];
            float4 s2 = red[2][n][l], s3 = red[3][n][l];
            int oc = oc0 + n * 16 + (l & 15);
            float bs = b1[oc];
            float4 s;
            s.x = fmaxf(s0.x + s1.x + s2.x + s3.x + bs, 0.f);
            s.y = fmaxf(s0.y + s1.y + s2.y + s3.y + bs, 0.f);
            s.z = fmaxf(s0.z + s1.z + s2.z + s3.z + bs, 0.f);
            s.w = fmaxf(s0.w + s1.w + s2.w + s3.w + bs, 0.f);
            int y = ty0 + m;
            int px0 = tx0 + (l >> 4) * 4;
            *(float4*)&h[(size_t)oc * NPX + y * WW + px0] = s;
        }
    }
}

// ---------------- K2: 1x1 convs (c-split partials) ----------------
__global__ __launch_bounds__(256) void conv1x1_part(const float* __restrict__ h,
                                                    const float* __restrict__ wc,
                                                    const float* __restrict__ wb,
                                                    float* __restrict__ psum) {
    __shared__ float wT[K2_CC][56];
    int tid = threadIdx.x;
    int px = blockIdx.x * 256 + tid;
    int g = blockIdx.y;
    int cb = g * K2_CC;
    for (int i = tid; i < K2_CC * 54; i += 256) {
        int c = i / 54, o = i - c * 54;
        float wv = (o < 18) ? wc[o * CMID + cb + c] : wb[(o - 18) * CMID + cb + c];
        wT[c][o] = wv;
    }
    __syncthreads();
    float acc[54];
#pragma unroll
    for (int o = 0; o < 54; o++) acc[o] = 0.f;
    for (int c = 0; c < K2_CC; c++) {
        float hv = h[(size_t)(cb + c) * NPX + px];
#pragma unroll
        for (int o = 0; o < 54; o++) acc[o] += wT[c][o] * hv;
    }
    for (int o = 0; o < 54; o++)
        psum[((size_t)g * 54 + o) * NPX + px] = acc[o];
}

// ---------------- K2b+K3 fused: reduce psum + proposals + histogram ----------------
// i indexed p-fastest: block = 256 consecutive pixels of one anchor a ->
// psum loads fully coalesced. Same add order as the old reduce (bias first,
// then g=0..15) -> bitwise-identical scores.
__global__ __launch_bounds__(256) void fused_props(const float* __restrict__ psum,
                                                   const float* __restrict__ bc,
                                                   const float* __restrict__ bb,
                                                   const float* __restrict__ info,
                                                   float* __restrict__ props,
                                                   float* __restrict__ scv,
                                                   unsigned int* __restrict__ hist) {
    int i = blockIdx.x * 256 + threadIdx.x;
    if (i >= NANCH) return;
    int a = i / NPX;          // 0..8 (block-uniform: NPX % 256 == 0)
    int p = i - a * NPX;
    int hy = p / WW, wx = p - hy * WW;

    float v0 = bc[a];
    float v1 = bc[a + 9];
    float v2 = bb[4 * a + 0];
    float v3 = bb[4 * a + 1];
    float v4 = bb[4 * a + 2];
    float v5 = bb[4 * a + 3];
    for (int g = 0; g < K2_CS; g++) {
        const float* pg = psum + ((size_t)g * 54) * NPX + p;
        v0 += pg[(size_t)a * NPX];
        v1 += pg[(size_t)(a + 9) * NPX];
        v2 += pg[(size_t)(18 + 4 * a + 0) * NPX];
        v3 += pg[(size_t)(18 + 4 * a + 1) * NPX];
        v4 += pg[(size_t)(18 + 4 * a + 2) * NPX];
        v5 += pg[(size_t)(18 + 4 * a + 3) * NPX];
    }

    float m = fmaxf(v0, v1);
    float e0 = expf(v0 - m), e1 = expf(v1 - m);
    float fg = e1 / (e0 + e1);

    float sx = wx * 16.f, sy = hy * 16.f;
    float ax1 = c_anch[a][0] + sx, ay1 = c_anch[a][1] + sy;
    float ax2 = c_anch[a][2] + sx, ay2 = c_anch[a][3] + sy;
    float wdt = ax2 - ax1 + 1.f;
    float hgt = ay2 - ay1 + 1.f;
    float cx = ax1 + 0.5f * wdt;
    float cy = ay1 + 0.5f * hgt;
    float pcx = v2 * wdt + cx;
    float pcy = v3 * hgt + cy;
    float pw = expf(v4) * wdt;
    float ph = expf(v5) * hgt;

    float imh = info[0], imw = info[1], iscale = info[2];
    float x1 = fminf(fmaxf(pcx - 0.5f * pw, 0.f), imw - 1.f);
    float y1 = fminf(fmaxf(pcy - 0.5f * ph, 0.f), imh - 1.f);
    float x2 = fminf(fmaxf(pcx + 0.5f * pw, 0.f), imw - 1.f);
    float y2 = fminf(fmaxf(pcy + 0.5f * ph, 0.f), imh - 1.f);

    float ms = 16.f * iscale;
    bool valid = ((x2 - x1 + 1.f) >= ms) && ((y2 - y1 + 1.f) >= ms);
    float s = valid ? fg : NEGV;

    int id = p * NA + a;                 // anchor index in reference (h,w,a) order
    props[(size_t)id * 4 + 0] = x1;
    props[(size_t)id * 4 + 1] = y1;
    props[(size_t)id * 4 + 2] = x2;
    props[(size_t)id * 4 + 3] = y2;
    scv[id] = s;
    atomicAdd(&hist[score_bin(s)], 1u);
}

// ---------------- K4: find threshold bin ----------------
__global__ __launch_bounds__(1024) void scan_hist(const unsigned int* __restrict__ hist,
                                                  unsigned int* __restrict__ params) {
    __shared__ unsigned int psum[1024];
    int tid = threadIdx.x;
    unsigned int s = 0;
    for (int k = 0; k < 16; k++) s += hist[tid * 16 + k];
    psum[tid] = s;
    __syncthreads();
    if (tid == 0) {
        unsigned int run = 0;
        int B = 0;
        int t;
        for (t = 1023; t >= 0; t--) {
            if (run + psum[t] >= PRE_NMS) break;
            run += psum[t];
        }
        if (t >= 0) {
            unsigned int r2 = run;
            B = t * 16;
            for (int b = t * 16 + 15; b >= t * 16; b--) {
                r2 += hist[b];
                if (r2 >= PRE_NMS) { B = b; break; }
            }
        }
        params[0] = (unsigned int)B;
    }
}

// ---------------- K5: gather candidates ----------------
__global__ __launch_bounds__(256) void gather_top(const float* __restrict__ scv,
                                                  const unsigned int* __restrict__ params,
                                                  unsigned long long* __restrict__ buf,
                                                  unsigned int* __restrict__ counter) {
    int i = blockIdx.x * 256 + threadIdx.x;
    if (i >= NANCH) return;
    float s = scv[i];
    if (score_bin(s) >= (int)params[0]) {
        unsigned int pos = atomicAdd(counter, 1u);
        if (pos < BUFCAP) {
            unsigned long long key = ((unsigned long long)fkey(s) << 32) |
                                     (unsigned int)(~(unsigned int)i);
            buf[pos] = key;
        }
    }
}

// ---------------- K6: bitonic sort (shfl-accelerated), emit top-6000 ----------------
__global__ __launch_bounds__(1024) void sort_top(unsigned long long* __restrict__ buf,
                                                 const unsigned int* __restrict__ counter,
                                                 const float* __restrict__ props,
                                                 float* __restrict__ top_boxes,
                                                 float* __restrict__ top_sc) {
    __shared__ unsigned long long arr[BUFCAP];   // 64 KiB
    int tid = threadIdx.x;
    int lane = tid & 63;
    int wvid = tid >> 6;
    unsigned int m = counter[0];
    if (m > BUFCAP) m = BUFCAP;
    for (int i = tid; i < BUFCAP; i += 1024) arr[i] = (i < (int)m) ? buf[i] : 0ULL;
    __syncthreads();
    for (int k = 2; k <= BUFCAP; k <<= 1) {
        for (int j = k >> 1; j >= 64; j >>= 1) {
            for (int i = tid; i < BUFCAP; i += 1024) {
                int l = i ^ j;
                if (l > i) {
                    unsigned long long a = arr[i], b = arr[l];
                    bool dir = ((i & k) == 0);   // descending overall
                    if (dir ? (a < b) : (a > b)) { arr[i] = b; arr[l] = a; }
                }
            }
            __syncthreads();
        }
        int jstart = (k >> 1) < 32 ? (k >> 1) : 32;
        for (int seg = wvid; seg < BUFCAP / 64; seg += 16) {
            int i = seg * 64 + lane;
            unsigned long long v = arr[i];
            bool dir = ((i & k) == 0);
            for (int j = jstart; j >= 1; j >>= 1) {
                unsigned long long v2 = __shfl_xor(v, j);
                bool islo = ((lane & j) == 0);
                unsigned long long vmin = v < v2 ? v : v2;
                unsigned long long vmax = v < v2 ? v2 : v;
                v = (dir == islo) ? vmax : vmin;
            }
            arr[i] = v;
        }
        __syncthreads();
    }
    for (int t = tid; t < PRE_NMS; t += 1024) {
        unsigned long long v = arr[t];
        unsigned int key = (unsigned int)(v >> 32);
        unsigned int idx = ~((unsigned int)v);
        top_sc[t] = fkey_inv(key);
        float4 bx = *(const float4*)&props[(size_t)idx * 4];
        *(float4*)&top_boxes[(size_t)t * 4] = bx;
    }
}

// ---------------- K7a: all-pairs IoU bitmask (upper triangle) ----------------
__global__ __launch_bounds__(256) void iou_mask(const float* __restrict__ top_boxes,
                                                unsigned long long* __restrict__ mask) {
    int wid = (blockIdx.x * 256 + threadIdx.x) >> 6;
    int lane = threadIdx.x & 63;
    if (wid >= PRE_NMS) return;
    float4 b = *(const float4*)&top_boxes[(size_t)wid * 4];
    float ab = (b.z - b.x + 1.f) * (b.w - b.y + 1.f);
    for (int cj = 0; cj < MASKW; cj++) {
        unsigned long long m = 0ULL;
        if ((cj + 1) * 64 > wid) {
            int j = cj * 64 + lane;
            bool sup = false;
            if (j < PRE_NMS && j >= wid) {
                float4 c = *(const float4*)&top_boxes[(size_t)j * 4];
                float ac = (c.z - c.x + 1.f) * (c.w - c.y + 1.f);
                float ix1 = fmaxf(b.x, c.x), iy1 = fmaxf(b.y, c.y);
                float ix2 = fminf(b.z, c.z), iy2 = fminf(b.w, c.w);
                float inter = fmaxf(ix2 - ix1 + 1.f, 0.f) * fmaxf(iy2 - iy1 + 1.f, 0.f);
                float iou = inter / (ab + ac - inter);
                sup = iou > 0.7f;
            }
            m = __ballot(sup);
        }
        if (lane == 0) mask[(size_t)wid * MASKW + cj] = m;
    }
}

// ---------------- K7b: greedy walk over sorted list ----------------
__global__ __launch_bounds__(64) void nms_greedy(const float* __restrict__ top_boxes,
                                                 const unsigned long long* __restrict__ mask,
                                                 float* __restrict__ out) {
    int lane = threadIdx.x;
    unsigned long long r0 = 0ULL;
    unsigned long long r1;
    if (lane < 29)      r1 = 0ULL;
    else if (lane == 29) r1 = ~((1ULL << 48) - 1);
    else                r1 = ~0ULL;
    for (int t = 0; t < POST_NMS; t++) {
        unsigned long long w0 = ~r0;
        unsigned long long w1 = ~r1;
        unsigned long long B0 = __ballot(w0 != 0ULL);
        unsigned long long B1 = __ballot(w1 != 0ULL);
        int pos = 0;
        if (B0) {
            int wl = __builtin_ctzll(B0);
            unsigned long long bits = __shfl(w0, wl);
            pos = wl * 64 + __builtin_ctzll(bits);
        } else if (B1) {
            int wl = __builtin_ctzll(B1);
            unsigned long long bits = __shfl(w1, wl);
            pos = (64 + wl) * 64 + __builtin_ctzll(bits);
        }
        if (lane == 0) {
            float4 bb = *(const float4*)&top_boxes[(size_t)pos * 4];
            out[t * 5 + 0] = 0.f;
            out[t * 5 + 1] = bb.x;
            out[t * 5 + 2] = bb.y;
            out[t * 5 + 3] = bb.z;
            out[t * 5 + 4] = bb.w;
        }
        r0 |= mask[(size_t)pos * MASKW + lane];
        if (lane < 30) r1 |= mask[(size_t)pos * MASKW + 64 + lane];
    }
}

// ---------------- launch ----------------
extern "C" void kernel_launch(void* const* d_in, const int* in_sizes, int n_in,
                              void* d_out, int out_size, void* d_ws, size_t ws_size,
                              hipStream_t stream) {
    const float* base = (const float*)d_in[0];
    const float* info = (const float*)d_in[1];
    const float* W1 = (const float*)d_in[3];
    const float* b1 = (const float*)d_in[4];
    const float* Wc = (const float*)d_in[5];
    const float* bc = (const float*)d_in[6];
    const float* Wb = (const float*)d_in[7];
    const float* Bb = (const float*)d_in[8];
    float* out = (float*)d_out;
    char* ws = (char*)d_ws;

    // Proven round-14 layout (60.6 MB extent). Only psum and mask alias
    // (xh region, dead after conv3_mfma / fused_props respectively).
    const size_t SZ_XT = (size_t)PYS * PXS * CIN * 2;        // 13,246,464
    const size_t SZ_WT = (size_t)9 * CMID * CIN * 2;         // 9,437,184
    const size_t OFF_XH = 0;
    const size_t OFF_XL = OFF_XH + SZ_XT;
    const size_t OFF_WH = OFF_XL + SZ_XT;
    const size_t OFF_WL = OFF_WH + SZ_WT;
    const size_t OFF_H  = OFF_WL + SZ_WT;                    // 45.4 MB
    const size_t OFF_SD   = OFF_H + (size_t)CMID * NPX * 4;  // 58.0 MB (spacer)
    const size_t OFF_PROPS= OFF_SD + (size_t)54 * NPX * 4;
    const size_t OFF_SCV  = OFF_PROPS + (size_t)NANCH * 16;
    const size_t OFF_HIST = OFF_SCV + (size_t)NANCH * 4;
    const size_t OFF_PAR  = OFF_HIST + (size_t)NBINS * 4;
    const size_t OFF_BUF  = OFF_PAR + 256;
    const size_t OFF_TB   = OFF_BUF + (size_t)BUFCAP * 8;
    const size_t OFF_TS   = OFF_TB + (size_t)PRE_NMS * 16;   // ends 60.6 MB
    const size_t OFF_PSUM = OFF_XH;                          // 21.2MB <- xh/xl dead
    const size_t OFF_MASK = OFF_XH;                          // 4.5MB <- psum dead

    _Float16* xh = (_Float16*)(ws + OFF_XH);
    _Float16* xl = (_Float16*)(ws + OFF_XL);
    _Float16* wh = (_Float16*)(ws + OFF_WH);
    _Float16* wl = (_Float16*)(ws + OFF_WL);
    float* h  = (float*)(ws + OFF_H);
    float* psum = (float*)(ws + OFF_PSUM);
    unsigned long long* mask = (unsigned long long*)(ws + OFF_MASK);
    float* props = (float*)(ws + OFF_PROPS);
    float* scv = (float*)(ws + OFF_SCV);
    unsigned int* hist = (unsigned int*)(ws + OFF_HIST);
    unsigned int* params = (unsigned int*)(ws + OFF_PAR);
    unsigned int* counter = params + 1;
    unsigned long long* buf = (unsigned long long*)(ws + OFF_BUF);
    float* top_boxes = (float*)(ws + OFF_TB);
    float* top_sc = (float*)(ws + OFF_TS);

    hipMemsetAsync(xh, 0, SZ_XT * 2, stream);    // zero xh+xl (contiguous) for halo
    hipMemsetAsync(hist, 0, (size_t)NBINS * 4 + 256, stream);

    prep_x<<<dim3(CIN / 64, NPX / 64), 256, 0, stream>>>(base, xh, xl);
    prep_w<<<CMID, 256, 0, stream>>>(W1, wh, wl);
    conv3_mfma<<<dim3(96, 16), 256, 0, stream>>>(xh, xl, wh, wl, b1, h);
    conv1x1_part<<<dim3(NPX / 256, K2_CS), 256, 0, stream>>>(h, Wc, Wb, psum);
    fused_props<<<NANCH / 256, 256, 0, stream>>>(psum, bc, Bb, info, props, scv, hist);
    scan_hist<<<1, 1024, 0, stream>>>(hist, params);
    gather_top<<<NANCH / 256, 256, 0, stream>>>(scv, params, buf, counter);
    sort_top<<<1, 1024, 0, stream>>>(buf, counter, props, top_boxes, top_sc);
    iou_mask<<<(PRE_NMS * 64 + 255) / 256, 256, 0, stream>>>(top_boxes, mask);
    nms_greedy<<<1, 64, 0, stream>>>(top_boxes, mask, out);
}